// Round 1
// baseline (1098.936 us; speedup 1.0000x reference)
//
#include <hip/hip_runtime.h>

typedef __attribute__((ext_vector_type(4))) float f32x4;
typedef __attribute__((ext_vector_type(8))) short bf16x8;

static __device__ __forceinline__ unsigned short f2bf(float f) {
  union { float f; unsigned int u; } v;
  v.f = f;
  unsigned int r = v.u + 0x7fffu + ((v.u >> 16) & 1u);  // RNE
  return (unsigned short)(r >> 16);
}

// ---------------------------------------------------------------------------
// Quantize (LSQ 4-bit fake-quant) + pack weights into fragment-linear bf16.
// pq[((cf*8+ks)*64+l)*8 + j] = bf16( round(clip(w[n][k]/alpha,-8,7))*alpha )
//   n = cf*16 + (l&15), k = ks*32 + (l>>4)*8 + j    (A-operand frag layout)
// ---------------------------------------------------------------------------
__global__ void lsq_pack(const float* __restrict__ w1, const float* __restrict__ a1,
                         const float* __restrict__ w2, const float* __restrict__ a2,
                         unsigned short* __restrict__ pq)
{
  int g = blockIdx.x * 256 + threadIdx.x;     // 0..16383 (8192 groups per matrix)
  int gg = g & 8191;
  const float* w = (g < 8192) ? w1 : w2;
  float alpha = (g < 8192) ? *a1 : *a2;
  unsigned short* dst = pq + ((g < 8192) ? 0 : 65536);
  int l  = gg & 63;
  int ks = (gg >> 6) & 7;
  int cf = gg >> 9;
  int n  = cf * 16 + (l & 15);
  int kb = ks * 32 + (l >> 4) * 8;
  const float* src = w + n * 256 + kb;
  unsigned short e[8];
  #pragma unroll
  for (int j = 0; j < 8; ++j) {
    float q = src[j] / alpha;
    q = fminf(fmaxf(q, -8.f), 7.f);
    q = rintf(q) * alpha;                     // rintf = round-half-even (matches jnp.round)
    e[j] = f2bf(q);
  }
  uint4 o;
  o.x = e[0] | ((unsigned)e[1] << 16);
  o.y = e[2] | ((unsigned)e[3] << 16);
  o.z = e[4] | ((unsigned)e[5] << 16);
  o.w = e[6] | ((unsigned)e[7] << 16);
  *(uint4*)(dst + gg * 8) = o;
}

// ---------------------------------------------------------------------------
// Layer 1: h = relu(x @ wq1^T + b1), h stored bf16.
// Swapped operands: A = weight frag (rows = output cols n), B = x frag
// (cols = x rows). C layout (m89): lane holds col xrow=l&15, rows n=4*(l>>4)+r
// -> per-lane 4 consecutive output columns => 8B packed bf16 stores.
// Weight frags cf 0..7 from LDS (64KB staged), cf 8..15 streamed from L2.
// ---------------------------------------------------------------------------
__global__ __launch_bounds__(512, 2) void lsq_g1(
    const float* __restrict__ x, const unsigned short* __restrict__ pq,
    const float* __restrict__ bias, unsigned short* __restrict__ h,
    int ntiles)
{
  __shared__ char lds[65536];
  {
    const uint4* s = (const uint4*)pq;
    uint4* d = (uint4*)lds;
    #pragma unroll 4
    for (int i = threadIdx.x; i < 4096; i += 512) d[i] = s[i];
  }
  __syncthreads();
  const int w  = threadIdx.x >> 6;
  const int l  = threadIdx.x & 63;
  const int l15 = l & 15, l4 = l >> 4;

  for (int t = blockIdx.x; t < ntiles; t += gridDim.x) {
    const size_t xrow = (size_t)t * 128 + w * 16 + l15;
    const float* xp = x + xrow * 256 + l4 * 8;
    // Load the full K-strip of x for these rows (16 independent dwordx4).
    f32x4 r0[8], r1[8];
    #pragma unroll
    for (int ks = 0; ks < 8; ++ks) {
      r0[ks] = *(const f32x4*)(xp + ks * 32);
      r1[ks] = *(const f32x4*)(xp + ks * 32 + 4);
    }
    bf16x8 bfr[8];
    #pragma unroll
    for (int ks = 0; ks < 8; ++ks) {
      bf16x8 b;
      #pragma unroll
      for (int j = 0; j < 4; ++j) {
        b[j]     = (short)f2bf(r0[ks][j]);
        b[j + 4] = (short)f2bf(r1[ks][j]);
      }
      bfr[ks] = b;
    }
    f32x4 acc[16] = {};
    #pragma unroll
    for (int ks = 0; ks < 8; ++ks) {
      #pragma unroll
      for (int cf = 0; cf < 16; ++cf) {
        const int off = ((cf * 8 + ks) * 64 + l) * 16;
        bf16x8 a = (cf < 8) ? *(const bf16x8*)(lds + off)
                            : *(const bf16x8*)((const char*)pq + off);
        acc[cf] = __builtin_amdgcn_mfma_f32_16x16x32_bf16(a, bfr[ks], acc[cf], 0, 0, 0);
      }
    }
    unsigned short* hp = h + xrow * 256;
    #pragma unroll
    for (int cf = 0; cf < 16; ++cf) {
      f32x4 bv = *(const f32x4*)(bias + cf * 16 + l4 * 4);
      float v0 = acc[cf][0] + bv[0]; v0 = v0 > 0.f ? v0 : 0.f;
      float v1 = acc[cf][1] + bv[1]; v1 = v1 > 0.f ? v1 : 0.f;
      float v2 = acc[cf][2] + bv[2]; v2 = v2 > 0.f ? v2 : 0.f;
      float v3 = acc[cf][3] + bv[3]; v3 = v3 > 0.f ? v3 : 0.f;
      uint2 o;
      o.x = f2bf(v0) | ((unsigned)f2bf(v1) << 16);
      o.y = f2bf(v2) | ((unsigned)f2bf(v3) << 16);
      *(uint2*)(hp + cf * 16 + l4 * 4) = o;
    }
  }
}

// ---------------------------------------------------------------------------
// Layer 2: out = sigmoid(h @ wq2^T + b2), fp32 out. Same structure; h is
// already bf16 so B-frags are direct 16B loads.
// ---------------------------------------------------------------------------
__global__ __launch_bounds__(512, 2) void lsq_g2(
    const unsigned short* __restrict__ h, const unsigned short* __restrict__ pq,
    const float* __restrict__ bias, float* __restrict__ out,
    int ntiles)
{
  __shared__ char lds[65536];
  {
    const uint4* s = (const uint4*)pq;
    uint4* d = (uint4*)lds;
    #pragma unroll 4
    for (int i = threadIdx.x; i < 4096; i += 512) d[i] = s[i];
  }
  __syncthreads();
  const int w  = threadIdx.x >> 6;
  const int l  = threadIdx.x & 63;
  const int l15 = l & 15, l4 = l >> 4;

  for (int t = blockIdx.x; t < ntiles; t += gridDim.x) {
    const size_t row = (size_t)t * 128 + w * 16 + l15;
    const unsigned short* hp = h + row * 256 + l4 * 8;
    bf16x8 bfr[8];
    #pragma unroll
    for (int ks = 0; ks < 8; ++ks) bfr[ks] = *(const bf16x8*)(hp + ks * 32);
    f32x4 acc[16] = {};
    #pragma unroll
    for (int ks = 0; ks < 8; ++ks) {
      #pragma unroll
      for (int cf = 0; cf < 16; ++cf) {
        const int off = ((cf * 8 + ks) * 64 + l) * 16;
        bf16x8 a = (cf < 8) ? *(const bf16x8*)(lds + off)
                            : *(const bf16x8*)((const char*)pq + off);
        acc[cf] = __builtin_amdgcn_mfma_f32_16x16x32_bf16(a, bfr[ks], acc[cf], 0, 0, 0);
      }
    }
    float* op = out + row * 256;
    #pragma unroll
    for (int cf = 0; cf < 16; ++cf) {
      f32x4 bv = *(const f32x4*)(bias + cf * 16 + l4 * 4);
      f32x4 o;
      #pragma unroll
      for (int r = 0; r < 4; ++r) {
        float z = acc[cf][r] + bv[r];
        o[r] = 1.f / (1.f + __expf(-z));
      }
      *(f32x4*)(op + cf * 16 + l4 * 4) = o;
    }
  }
}

// ---------------------------------------------------------------------------
extern "C" void kernel_launch(void* const* d_in, const int* in_sizes, int n_in,
                              void* d_out, int out_size, void* d_ws, size_t ws_size,
                              hipStream_t stream)
{
  const float* x  = (const float*)d_in[0];
  const float* w1 = (const float*)d_in[1];
  const float* b1 = (const float*)d_in[2];
  const float* a1 = (const float*)d_in[3];
  const float* w2 = (const float*)d_in[4];
  const float* b2 = (const float*)d_in[5];
  const float* a2 = (const float*)d_in[6];
  float* out = (float*)d_out;

  unsigned short* pq   = (unsigned short*)d_ws;   // 2 x 65536 ushort (256KB) packed weights
  unsigned short* hbuf = pq + 131072;             // bf16 h scratch (chunked if ws is small)

  long long totalRows = (long long)in_sizes[0] / 256;

  long long capRows = 0;
  if (ws_size > 262144) capRows = (long long)((ws_size - 262144) / 512);  // 512B per h row
  capRows = (capRows / 128) * 128;
  if (capRows < 128) capRows = 128;               // minimal tile; assume ws suffices
  if (capRows > totalRows) capRows = totalRows;

  lsq_pack<<<64, 256, 0, stream>>>(w1, a1, w2, a2, pq);

  for (long long r0 = 0; r0 < totalRows; r0 += capRows) {
    long long rows = totalRows - r0;
    if (rows > capRows) rows = capRows;
    int ntiles = (int)(rows / 128);
    int grid = ntiles < 256 ? ntiles : 256;
    lsq_g1<<<grid, 512, 0, stream>>>(x + r0 * 256, pq, b1, hbuf, ntiles);
    lsq_g2<<<grid, 512, 0, stream>>>(hbuf, pq + 65536, b2, out + r0 * 256, ntiles);
  }
}

// Round 2
// 196.305 us; speedup vs baseline: 5.5981x; 5.5981x over previous
//
#include <hip/hip_runtime.h>

typedef __attribute__((ext_vector_type(4))) float f32x4;
typedef __attribute__((ext_vector_type(8))) short bf16x8;

static __device__ __forceinline__ unsigned short f2bf(float f) {
  union { float f; unsigned int u; } v;
  v.f = f;
  unsigned int r = v.u + 0x7fffu + ((v.u >> 16) & 1u);  // RNE
  return (unsigned short)(r >> 16);
}

static __device__ __forceinline__ void gload16(const void* g, void* l) {
  __builtin_amdgcn_global_load_lds(
      (const __attribute__((address_space(1))) unsigned int*)g,
      (__attribute__((address_space(3))) unsigned int*)l, 16, 0, 0);
}

// ---------------------------------------------------------------------------
// LSQ 4-bit fake-quant + pack to fragment-linear bf16.
// Frag content (both): lane l holds wq[n][k], n = cf*16 + (l&15),
// k = ks*32 + (l>>4)*8 + j.
// w1 frag address: ((cf*8 + ks)*64 + l)*8   (cf-major -> cf-pair chunks)
// w2 frag address: ((ks*16 + cf)*64 + l)*8  (ks-major -> ks-slice chunks)
// ---------------------------------------------------------------------------
__global__ void lsq_pack(const float* __restrict__ w1, const float* __restrict__ a1,
                         const float* __restrict__ w2, const float* __restrict__ a2,
                         unsigned short* __restrict__ pq)
{
  int g = blockIdx.x * 256 + threadIdx.x;     // 0..16383
  int gg = g & 8191;
  const float* w = (g < 8192) ? w1 : w2;
  float alpha = (g < 8192) ? *a1 : *a2;
  unsigned short* dst = pq + ((g < 8192) ? 0 : 65536);
  int l  = gg & 63;
  int ks = (gg >> 6) & 7;
  int cf = gg >> 9;
  int n  = cf * 16 + (l & 15);
  int kb = ks * 32 + (l >> 4) * 8;
  const float* src = w + n * 256 + kb;
  unsigned short e[8];
  #pragma unroll
  for (int j = 0; j < 8; ++j) {
    float q = src[j] / alpha;
    q = fminf(fmaxf(q, -8.f), 7.f);
    q = rintf(q) * alpha;                     // round-half-even == jnp.round
    e[j] = f2bf(q);
  }
  uint4 o;
  o.x = e[0] | ((unsigned)e[1] << 16);
  o.y = e[2] | ((unsigned)e[3] << 16);
  o.z = e[4] | ((unsigned)e[5] << 16);
  o.w = e[6] | ((unsigned)e[7] << 16);
  int di = (g < 8192) ? ((cf * 8 + ks) * 64 + l) : ((ks * 16 + cf) * 64 + l);
  *(uint4*)(dst + di * 8) = o;
}

// ---------------------------------------------------------------------------
// Fused: out = sigmoid(relu(x@wq1^T + b1) @ wq2^T + b2)
// Block = 512 threads (8 waves), block-tile = 256 rows, wave-tile = 32 rows
// (2 groups of 16, R=2 register reuse of weight frags).
// 8 rounds/tile; round r: layer-1 cf {2r,2r+1} -> h ch 32r..32r+31 staged in
// wave-private LDS (XOR swizzle) -> layer-2 partial ks2=r.
// Weights double-buffered in LDS via global_load_lds; 1 barrier/round.
// LDS: 2*16K (w1) + 2*16K (w2) + 8*2K (h) = 80 KB -> 1 block/CU.
// ---------------------------------------------------------------------------
__global__ __launch_bounds__(512, 2) void lsq_fused(
    const float* __restrict__ x, const unsigned short* __restrict__ pqw,
    const float* __restrict__ b1, const float* __restrict__ b2,
    float* __restrict__ out, int ntiles)
{
  __shared__ __align__(16) char w1lds[2][16384];
  __shared__ __align__(16) char w2lds[2][16384];
  __shared__ __align__(16) char hlds[8][2048];

  const int tid  = threadIdx.x;
  const int lane = tid & 63;
  const int w    = tid >> 6;
  const int l15  = lane & 15;
  const int l4   = lane >> 4;
  const int swz  = (l15 & 3) << 4;           // h-stage bank swizzle (bits 4-5)
  const char* pq1 = (const char*)pqw;            // 128 KB (8 chunks of 16 KB)
  const char* pq2 = (const char*)pqw + 131072;   // 128 KB (8 slices of 16 KB)
  const int wb = w * 1024;
  const int lo = wb + lane * 16;

  // prologue: stage chunk 0 into buffer 0
  gload16(pq1 + lo,        &w1lds[0][0]    + wb);
  gload16(pq1 + 8192 + lo, &w1lds[0][8192] + wb);
  gload16(pq2 + lo,        &w2lds[0][0]    + wb);
  gload16(pq2 + 8192 + lo, &w2lds[0][8192] + wb);
  __syncthreads();

  int gr = 0;                                 // global round counter (chunk = gr&7)
  for (int t = blockIdx.x; t < ntiles; t += gridDim.x) {
    const int rowbase = t * 256 + w * 32;

    // Load + convert x fragments for both 16-row groups (held all tile).
    bf16x8 xf[2][8];
    #pragma unroll
    for (int g = 0; g < 2; ++g) {
      const float* xp = x + (size_t)(rowbase + g * 16 + l15) * 256 + l4 * 8;
      #pragma unroll
      for (int ks = 0; ks < 8; ++ks) {
        f32x4 r0 = *(const f32x4*)(xp + ks * 32);
        f32x4 r1 = *(const f32x4*)(xp + ks * 32 + 4);
        bf16x8 b;
        #pragma unroll
        for (int j = 0; j < 4; ++j) {
          b[j]     = (short)f2bf(r0[j]);
          b[j + 4] = (short)f2bf(r1[j]);
        }
        xf[g][ks] = b;
      }
    }

    f32x4 acc2[2][16];
    const f32x4 fzero = {0.f, 0.f, 0.f, 0.f};
    #pragma unroll
    for (int g = 0; g < 2; ++g)
      #pragma unroll
      for (int c = 0; c < 16; ++c)
        acc2[g][c] = fzero;

    for (int r = 0; r < 8; ++r) {
      const int cb = gr & 1;
      const int nb = cb ^ 1;
      const int nc = (gr + 1) & 7;
      // Stage next chunk into nb. Safe: nb's last readers finished before the
      // barrier that ended the previous round.
      gload16(pq1 + nc * 16384 + lo,        &w1lds[nb][0]    + wb);
      gload16(pq1 + nc * 16384 + 8192 + lo, &w1lds[nb][8192] + wb);
      gload16(pq2 + nc * 16384 + lo,        &w2lds[nb][0]    + wb);
      gload16(pq2 + nc * 16384 + 8192 + lo, &w2lds[nb][8192] + wb);

      // ---- phase A: layer-1 for cf pair {2r, 2r+1}, both groups ----
      #pragma unroll
      for (int c = 0; c < 2; ++c) {
        f32x4 a0 = fzero, a1v = fzero;
        #pragma unroll
        for (int ks = 0; ks < 8; ++ks) {
          bf16x8 wf = *(const bf16x8*)(&w1lds[cb][0] + c * 8192 + ks * 1024 + lane * 16);
          a0  = __builtin_amdgcn_mfma_f32_16x16x32_bf16(wf, xf[0][ks], a0, 0, 0, 0);
          a1v = __builtin_amdgcn_mfma_f32_16x16x32_bf16(wf, xf[1][ks], a1v, 0, 0, 0);
        }
        const int cf = 2 * r + c;
        f32x4 bv = *(const f32x4*)(b1 + cf * 16 + l4 * 4);
        const int hb = (c * 32 + l4 * 8) ^ swz;
        {
          float v0 = a0[0] + bv[0]; v0 = v0 > 0.f ? v0 : 0.f;
          float v1 = a0[1] + bv[1]; v1 = v1 > 0.f ? v1 : 0.f;
          float v2 = a0[2] + bv[2]; v2 = v2 > 0.f ? v2 : 0.f;
          float v3 = a0[3] + bv[3]; v3 = v3 > 0.f ? v3 : 0.f;
          uint2 o;
          o.x = f2bf(v0) | ((unsigned)f2bf(v1) << 16);
          o.y = f2bf(v2) | ((unsigned)f2bf(v3) << 16);
          *(uint2*)(&hlds[w][0] + l15 * 64 + hb) = o;
        }
        {
          float v0 = a1v[0] + bv[0]; v0 = v0 > 0.f ? v0 : 0.f;
          float v1 = a1v[1] + bv[1]; v1 = v1 > 0.f ? v1 : 0.f;
          float v2 = a1v[2] + bv[2]; v2 = v2 > 0.f ? v2 : 0.f;
          float v3 = a1v[3] + bv[3]; v3 = v3 > 0.f ? v3 : 0.f;
          uint2 o;
          o.x = f2bf(v0) | ((unsigned)f2bf(v1) << 16);
          o.y = f2bf(v2) | ((unsigned)f2bf(v3) << 16);
          *(uint2*)(&hlds[w][0] + (16 + l15) * 64 + hb) = o;
        }
      }
      // Keep the h ds_reads below from moving above the ds_writes.
      __builtin_amdgcn_sched_barrier(0);

      // ---- phase B: layer-2 partial, ks2 = r (wave-private h slice) ----
      bf16x8 hf0 = *(const bf16x8*)(&hlds[w][0] + l15 * 64        + ((l4 * 16) ^ swz));
      bf16x8 hf1 = *(const bf16x8*)(&hlds[w][0] + (16 + l15) * 64 + ((l4 * 16) ^ swz));
      #pragma unroll
      for (int c2 = 0; c2 < 16; ++c2) {
        bf16x8 wf2 = *(const bf16x8*)(&w2lds[cb][0] + c2 * 1024 + lane * 16);
        acc2[0][c2] = __builtin_amdgcn_mfma_f32_16x16x32_bf16(wf2, hf0, acc2[0][c2], 0, 0, 0);
        acc2[1][c2] = __builtin_amdgcn_mfma_f32_16x16x32_bf16(wf2, hf1, acc2[1][c2], 0, 0, 0);
      }
      ++gr;
      __syncthreads();   // drains staging vmcnt; retires all readers of cb
    }

    // ---- tile epilogue: bias2 + sigmoid + store ----
    #pragma unroll
    for (int g = 0; g < 2; ++g) {
      float* op = out + (size_t)(rowbase + g * 16 + l15) * 256 + l4 * 4;
      #pragma unroll
      for (int c2 = 0; c2 < 16; ++c2) {
        f32x4 bv = *(const f32x4*)(b2 + c2 * 16 + l4 * 4);
        f32x4 o;
        #pragma unroll
        for (int j = 0; j < 4; ++j) {
          float z = acc2[g][c2][j] + bv[j];
          o[j] = 1.f / (1.f + __expf(-z));
        }
        *(f32x4*)(op + c2 * 16) = o;
      }
    }
  }
}

// ---------------------------------------------------------------------------
extern "C" void kernel_launch(void* const* d_in, const int* in_sizes, int n_in,
                              void* d_out, int out_size, void* d_ws, size_t ws_size,
                              hipStream_t stream)
{
  const float* x  = (const float*)d_in[0];
  const float* w1 = (const float*)d_in[1];
  const float* b1 = (const float*)d_in[2];
  const float* a1 = (const float*)d_in[3];
  const float* w2 = (const float*)d_in[4];
  const float* b2 = (const float*)d_in[5];
  const float* a2 = (const float*)d_in[6];
  float* out = (float*)d_out;

  unsigned short* pq = (unsigned short*)d_ws;   // 256 KB packed weights

  long long totalRows = (long long)in_sizes[0] / 256;
  int ntiles = (int)(totalRows / 256);          // 1024 at N=262144

  lsq_pack<<<64, 256, 0, stream>>>(w1, a1, w2, a2, pq);

  int grid = ntiles < 256 ? ntiles : 256;
  lsq_fused<<<grid, 512, 0, stream>>>(x, pq, b1, b2, out, ntiles);
}